// Round 3
// baseline (553.093 us; speedup 1.0000x reference)
//
#include <hip/hip_runtime.h>

typedef unsigned short u16;
typedef unsigned int u32;
typedef __bf16 bf16x8 __attribute__((ext_vector_type(8)));
typedef float f32x4 __attribute__((ext_vector_type(4)));
typedef u16 u16x8 __attribute__((ext_vector_type(8)));
typedef u16 u16x4 __attribute__((ext_vector_type(4)));

#define IN_CH 256
#define HID 64
#define NGRP 4              // channel groups: 16 ch = 32 B per node-slice, 3.2 MB/group
#define BSHIFT 8            // 256 nodes per bucket
#define BNODES 256
#define NBUK 391            // ceil(100000 / 256)
#define BCAP 10240          // avg 8184 edges/bucket; +22 sigma headroom
#define TILE 8192           // edges per partition tile

__device__ __forceinline__ u16 f2bf(float f) {
  union { float f; unsigned u; } v; v.f = f;
  unsigned r = v.u + 0x7FFFu + ((v.u >> 16) & 1u);  // RNE
  return (u16)(r >> 16);
}
__device__ __forceinline__ float bf2f(u16 h) {
  union { unsigned u; float f; } v; v.u = ((unsigned)h) << 16;
  return v.f;
}

// transpose + bf16-convert weights: w1t[n][k] (64x256), w2t[n][k] (64x64)
__global__ void k_wprep(const float* __restrict__ W1, const float* __restrict__ W2,
                        u16* __restrict__ w1t, u16* __restrict__ w2t) {
  int t = blockIdx.x * blockDim.x + threadIdx.x;
  if (t < 64 * 256) {
    int n = t >> 8, k = t & 255;
    w1t[t] = f2bf(W1[k * 64 + n]);
  }
  int t2 = t - 64 * 256;
  if (t2 >= 0 && t2 < 64 * 64) {
    int n = t2 >> 6, k = t2 & 63;
    w2t[t2] = f2bf(W2[k * 64 + n]);
  }
}

// ---------------- phase A: LDS-staged bucket partition ----------------
// Edge packed as u32: src (bits 0-19) | dloc (bits 20-27). Int LDS atomics only.

__global__ __launch_bounds__(1024) void k_part(const int* __restrict__ e_src,
                                               const int* __restrict__ e_dst,
                                               int* __restrict__ bcnt,
                                               u32* __restrict__ bedge, int E) {
  __shared__ int lcnt[512];
  __shared__ int lscan[512];
  __shared__ int gbase[512];
  __shared__ int wsum[8];
  __shared__ u32 stag[TILE];
  __shared__ int dest[TILE];
  int t = threadIdx.x;
  int base = blockIdx.x * TILE;
  int here = E - base; if (here > TILE) here = TILE;

  if (t < 512) lcnt[t] = 0;
  __syncthreads();

  u32 m[8]; int bk[8]; int rk[8];
#pragma unroll
  for (int k = 0; k < 8; ++k) {
    int e = base + t + k * 1024;
    if (e < E) {
      int s = e_src[e], d = e_dst[e];
      bk[k] = d >> BSHIFT;
      m[k] = (u32)s | ((u32)(d & (BNODES - 1)) << 20);
      rk[k] = atomicAdd(&lcnt[bk[k]], 1);
    } else bk[k] = -1;
  }
  __syncthreads();

  // exclusive scan of lcnt[0..511] by threads 0..511 (8 waves)
  int lane = t & 63, w = t >> 6;
  int v = 0, x = 0;
  if (t < 512) { v = lcnt[t]; x = v; }
#pragma unroll
  for (int off = 1; off < 64; off <<= 1) {
    int y = __shfl_up(x, off);
    if (lane >= off) x += y;
  }
  if (t < 512 && lane == 63) wsum[w] = x;
  __syncthreads();
  if (t < 512) {
    int wo = 0;
    for (int i = 0; i < w; ++i) wo += wsum[i];
    lscan[t] = x - v + wo;
  }
  __syncthreads();

  // reserve global space per bucket
  if (t < NBUK) gbase[t] = t * BCAP + atomicAdd(&bcnt[t], lcnt[t]);
  __syncthreads();

  // place into LDS staging ordered by bucket
#pragma unroll
  for (int k = 0; k < 8; ++k) {
    if (bk[k] >= 0) {
      int p = lscan[bk[k]] + rk[k];
      stag[p] = m[k];
      dest[p] = gbase[bk[k]] + rk[k];
    }
  }
  __syncthreads();

  // coalesced copy-out (runs of same-bucket edges are contiguous)
#pragma unroll
  for (int k = 0; k < 8; ++k) {
    int p = t + k * 1024;
    if (p < here) bedge[dest[p]] = stag[p];
  }
}

// ---------------- phase B: per-bucket counting sort by dst (in-place) ----------------
// Emits rptr/rcnt/dinv. Int LDS atomics only.

__global__ __launch_bounds__(1024) void k_sort(const int* __restrict__ bcnt,
                                               u32* __restrict__ bedge,
                                               int* __restrict__ rptr,
                                               int* __restrict__ rcnt,
                                               float* __restrict__ dinv, int N) {
  __shared__ u32 stag[BCAP];     // 40 KB
  __shared__ int hist[BNODES];
  __shared__ int cur[BNODES];
  __shared__ int wsum4[4];
  int b = blockIdx.x, t = threadIdx.x;
  if (t < BNODES) hist[t] = 0;
  __syncthreads();
  int n = bcnt[b]; if (n > BCAP) n = BCAP;
  u32* be = bedge + (size_t)b * BCAP;

  for (int i = t; i < n; i += 1024) atomicAdd(&hist[be[i] >> 20], 1);
  __syncthreads();

  // exclusive scan of hist[0..255] by threads 0..255 (4 waves)
  int lane = t & 63, w = t >> 6;
  int v = 0, x = 0;
  if (t < BNODES) { v = hist[t]; x = v; }
#pragma unroll
  for (int off = 1; off < 64; off <<= 1) {
    int y = __shfl_up(x, off);
    if (lane >= off) x += y;
  }
  if (t < BNODES && lane == 63) wsum4[w] = x;
  __syncthreads();
  if (t < BNODES) {
    int wo = 0;
    for (int i = 0; i < w; ++i) wo += wsum4[i];
    int ex = x - v + wo;
    cur[t] = ex;
    int node = (b << BSHIFT) + t;
    if (node < N) {
      rptr[node] = b * BCAP + ex;
      rcnt[node] = v;
      dinv[node] = rsqrtf((float)(v + 1));  // +1 self-loop
    }
  }
  __syncthreads();

  // rank + scatter into LDS (sorted by dloc)
  for (int i = t; i < n; i += 1024) {
    u32 m = be[i];
    int p = atomicAdd(&cur[m >> 20], 1);
    stag[p] = m;
  }
  __syncthreads();

  // in-place coalesced writeback
  for (int i = t; i < n; i += 1024) be[i] = stag[i];
}

// ---------------- gemm1 (MFMA 16x16x32 bf16), wave = 16 rows x ALL 64 cols ----------------
// A[m=lane&15][k=quad*8+j], B[n=lane&15][k=quad*8+j], D: col=lane&15, row=quad*4+reg.
// h'[row] = dinv[row] * (x@W1)[row].
// Output written in channel-GROUPED layout hg[g][row][16] (g = c) so the agg
// gathers from a 3.2-MB per-group slice that fits a 4-MB per-XCD L2.
// launch_bounds(256,1): waves-per-eu=1 frees the register allocator so the
// 16 hoisted A-loads stay clustered.

__global__ __launch_bounds__(256, 1) void k_gemm1(const float* __restrict__ x,
                                                  const u16* __restrict__ w1t,
                                                  const float* __restrict__ dinv,
                                                  u16* __restrict__ hg, int N) {
  int lane = threadIdx.x & 63;
  int wave = threadIdx.x >> 6;
  int rowbase = (blockIdx.x * 4 + wave) * 16;
  if (rowbase >= N) return;  // N % 16 == 0: tiles never straddle
  int mn = lane & 15, quad = lane >> 4;
  const float* arow = x + (size_t)(rowbase + mn) * IN_CH + quad * 8;

  // hoist all 16 A loads (64 VGPR) -> one vmcnt wait
  float4 a[16];
#pragma unroll
  for (int kc = 0; kc < 8; ++kc) {
    a[2 * kc] = *(const float4*)(arow + kc * 32);
    a[2 * kc + 1] = *(const float4*)(arow + kc * 32 + 4);
  }
  // convert once to bf16 frags (32 VGPR)
  u16x8 au[8];
#pragma unroll
  for (int kc = 0; kc < 8; ++kc) {
    float4 a0 = a[2 * kc], a1 = a[2 * kc + 1];
    au[kc][0] = f2bf(a0.x); au[kc][1] = f2bf(a0.y);
    au[kc][2] = f2bf(a0.z); au[kc][3] = f2bf(a0.w);
    au[kc][4] = f2bf(a1.x); au[kc][5] = f2bf(a1.y);
    au[kc][6] = f2bf(a1.z); au[kc][7] = f2bf(a1.w);
  }

  f32x4 acc[4] = {{0.f, 0.f, 0.f, 0.f}, {0.f, 0.f, 0.f, 0.f},
                  {0.f, 0.f, 0.f, 0.f}, {0.f, 0.f, 0.f, 0.f}};
#pragma unroll
  for (int c = 0; c < 4; ++c) {
    const u16* brow = w1t + (c * 16 + mn) * IN_CH + quad * 8;
    u16x8 bu[8];  // clustered, L1-hot (B is 32 KB shared chip-wide)
#pragma unroll
    for (int kc = 0; kc < 8; ++kc) bu[kc] = *(const u16x8*)(brow + kc * 32);
#pragma unroll
    for (int kc = 0; kc < 8; ++kc)
      acc[c] = __builtin_amdgcn_mfma_f32_16x16x32_bf16(
          __builtin_bit_cast(bf16x8, au[kc]), __builtin_bit_cast(bf16x8, bu[kc]),
          acc[c], 0, 0, 0);
  }
#pragma unroll
  for (int r = 0; r < 4; ++r) {
    int row = rowbase + quad * 4 + r;
    float dv = dinv[row];
#pragma unroll
    for (int c = 0; c < 4; ++c)
      hg[((size_t)c * N + row) * 16 + mn] = f2bf(dv * acc[c][r]);
  }
}

// gemm2: A = g1 standard [N][64] layout; output written GROUPED hg[g][row][16].
__global__ __launch_bounds__(256) void k_gemm2(const u16* __restrict__ g1,
                                               const u16* __restrict__ w2t,
                                               const float* __restrict__ dinv,
                                               u16* __restrict__ hg, int N) {
  int lane = threadIdx.x & 63;
  int wave = threadIdx.x >> 6;
  int rowbase = blockIdx.x * 16;
  int colgrp = wave;  // 16-channel group
  int mn = lane & 15, quad = lane >> 4;
  const u16* arow = g1 + (size_t)(rowbase + mn) * HID + quad * 8;
  const u16* brow = w2t + (colgrp * 16 + mn) * HID + quad * 8;
  u16x8 au0 = *(const u16x8*)(arow);
  u16x8 au1 = *(const u16x8*)(arow + 32);
  u16x8 bu0 = *(const u16x8*)(brow);
  u16x8 bu1 = *(const u16x8*)(brow + 32);
  f32x4 acc = {0.f, 0.f, 0.f, 0.f};
  acc = __builtin_amdgcn_mfma_f32_16x16x32_bf16(
      __builtin_bit_cast(bf16x8, au0), __builtin_bit_cast(bf16x8, bu0), acc, 0, 0, 0);
  acc = __builtin_amdgcn_mfma_f32_16x16x32_bf16(
      __builtin_bit_cast(bf16x8, au1), __builtin_bit_cast(bf16x8, bu1), acc, 0, 0, 0);
#pragma unroll
  for (int r = 0; r < 4; ++r) {
    int row = rowbase + quad * 4 + r;
    hg[((size_t)colgrp * N + row) * 16 + mn] = f2bf(dinv[row] * acc[r]);
  }
}

// ---------------- aggregation: channel-grouped, XCD-pinned gathers ----------------
// out[i] = dinv_i * (sum_e h'[src_e] + h'[i]) + bias
// Rounds 0/1 A/B showed agg is MISS-TRAFFIC-bound, not issue-bound
// (4x fewer gather instrs, same 64 us; FETCH_SIZE 160 MB vs 12.8 MB unique h).
// Random 128-B row gathers over a 12.8-MB table miss a 4-MB per-XCD L2 ~40%
// of the time and the miss stream runs at only ~2.9 TB/s.
// Fix: h stored as hg[4][N][16] (3.2 MB per group). blockIdx = chunk*8+sub;
// g = sub>>1 pins one group per XCD pair (round-robin blockIdx->XCD), so each
// XCD's L2 holds its whole slice -> gathers ~always hit after warmup.
// Edge list re-read once per group (4 x 12.8 MB) but via nontemporal loads:
// streaming, L3-hot after first group, and doesn't evict the slice.
// Wave per (node, group): lane = slot*4+cb; slot=edge 0..15, cb=4 channels.
// 8 B/lane gathers, 16 edges per instruction; shfl_xor(4/8/16/32) fold;
// lanes 0-3 add self-loop + scale + bias, one 64-B store.

template <bool RELU, bool BF16OUT>
__global__ __launch_bounds__(256, 4) void k_agg(const u16* __restrict__ hg,
                                                const int* __restrict__ rptr,
                                                const int* __restrict__ rcnt,
                                                const u32* __restrict__ sedge,
                                                const float* __restrict__ bias,
                                                void* __restrict__ outv, int N) {
  int sub = blockIdx.x & 7;
  int chunk = blockIdx.x >> 3;
  int g = sub >> 1;       // channel group, pinned per XCD pair
  int half = sub & 1;
  int wave = threadIdx.x >> 6;
  int lane = threadIdx.x & 63;
  int wid = (chunk * 2 + half) * 4 + wave;
  if (wid >= N) return;
  int slot = lane >> 2;   // edge slot 0..15
  int cb = lane & 3;      // channels g*16 + cb*4 .. +3
  int start = __builtin_amdgcn_readfirstlane(rptr[wid]);
  int len = __builtin_amdgcn_readfirstlane(rcnt[wid]);
  float di = rsqrtf((float)(len + 1));
  const u16* hgg = hg + (((size_t)g * N) << 4);
  // self-loop slice (L2-hot, broadcast across slots)
  u16x4 sv = *(const u16x4*)(hgg + (((size_t)wid) << 4) + (cb << 2));
  float a0 = 0.f, a1 = 0.f, a2 = 0.f, a3 = 0.f;
  const u32* se = sedge + start;
  int j = 0;
  // main: 64 edges / iter = 4 packs in flight
  for (; j + 64 <= len; j += 64) {
    u32 w0 = __builtin_nontemporal_load(se + j + slot);
    u32 w1 = __builtin_nontemporal_load(se + j + 16 + slot);
    u32 w2 = __builtin_nontemporal_load(se + j + 32 + slot);
    u32 w3 = __builtin_nontemporal_load(se + j + 48 + slot);
    u16x4 v0 = *(const u16x4*)(hgg + (((size_t)(w0 & 0xFFFFF)) << 4) + (cb << 2));
    u16x4 v1 = *(const u16x4*)(hgg + (((size_t)(w1 & 0xFFFFF)) << 4) + (cb << 2));
    u16x4 v2 = *(const u16x4*)(hgg + (((size_t)(w2 & 0xFFFFF)) << 4) + (cb << 2));
    u16x4 v3 = *(const u16x4*)(hgg + (((size_t)(w3 & 0xFFFFF)) << 4) + (cb << 2));
    a0 += bf2f(v0[0]); a1 += bf2f(v0[1]); a2 += bf2f(v0[2]); a3 += bf2f(v0[3]);
    a0 += bf2f(v1[0]); a1 += bf2f(v1[1]); a2 += bf2f(v1[2]); a3 += bf2f(v1[3]);
    a0 += bf2f(v2[0]); a1 += bf2f(v2[1]); a2 += bf2f(v2[2]); a3 += bf2f(v2[3]);
    a0 += bf2f(v3[0]); a1 += bf2f(v3[1]); a2 += bf2f(v3[2]); a3 += bf2f(v3[3]);
  }
  if (j + 32 <= len) {
    u32 w0 = __builtin_nontemporal_load(se + j + slot);
    u32 w1 = __builtin_nontemporal_load(se + j + 16 + slot);
    u16x4 v0 = *(const u16x4*)(hgg + (((size_t)(w0 & 0xFFFFF)) << 4) + (cb << 2));
    u16x4 v1 = *(const u16x4*)(hgg + (((size_t)(w1 & 0xFFFFF)) << 4) + (cb << 2));
    a0 += bf2f(v0[0]); a1 += bf2f(v0[1]); a2 += bf2f(v0[2]); a3 += bf2f(v0[3]);
    a0 += bf2f(v1[0]); a1 += bf2f(v1[1]); a2 += bf2f(v1[2]); a3 += bf2f(v1[3]);
    j += 32;
  }
  if (j + 16 <= len) {
    u32 w0 = __builtin_nontemporal_load(se + j + slot);
    u16x4 v0 = *(const u16x4*)(hgg + (((size_t)(w0 & 0xFFFFF)) << 4) + (cb << 2));
    a0 += bf2f(v0[0]); a1 += bf2f(v0[1]); a2 += bf2f(v0[2]); a3 += bf2f(v0[3]);
    j += 16;
  }
  // predicated 16-edge tail (invalid slots multiply by 0)
  for (; j < len; j += 16) {
    int idx = j + slot;
    u32 w = __builtin_nontemporal_load(se + (idx < len ? idx : len - 1));
    u16x4 v = *(const u16x4*)(hgg + (((size_t)(w & 0xFFFFF)) << 4) + (cb << 2));
    float m = idx < len ? 1.f : 0.f;
    a0 = fmaf(m, bf2f(v[0]), a0); a1 = fmaf(m, bf2f(v[1]), a1);
    a2 = fmaf(m, bf2f(v[2]), a2); a3 = fmaf(m, bf2f(v[3]), a3);
  }
  // fold the 16 edge slots (lanes sharing cb differ by multiples of 4)
  a0 += __shfl_xor(a0, 4); a0 += __shfl_xor(a0, 8); a0 += __shfl_xor(a0, 16); a0 += __shfl_xor(a0, 32);
  a1 += __shfl_xor(a1, 4); a1 += __shfl_xor(a1, 8); a1 += __shfl_xor(a1, 16); a1 += __shfl_xor(a1, 32);
  a2 += __shfl_xor(a2, 4); a2 += __shfl_xor(a2, 8); a2 += __shfl_xor(a2, 16); a2 += __shfl_xor(a2, 32);
  a3 += __shfl_xor(a3, 4); a3 += __shfl_xor(a3, 8); a3 += __shfl_xor(a3, 16); a3 += __shfl_xor(a3, 32);
  if (slot == 0) {
    a0 += bf2f(sv[0]); a1 += bf2f(sv[1]); a2 += bf2f(sv[2]); a3 += bf2f(sv[3]);
    const float* bp = bias + g * 16 + (cb << 2);
    float b0 = bp[0], b1_ = bp[1], b2_ = bp[2], b3 = bp[3];
    a0 = di * a0 + b0; a1 = di * a1 + b1_;
    a2 = di * a2 + b2_; a3 = di * a3 + b3;
    if (RELU) {
      a0 = fmaxf(a0, 0.f); a1 = fmaxf(a1, 0.f);
      a2 = fmaxf(a2, 0.f); a3 = fmaxf(a3, 0.f);
    }
    if (BF16OUT) {
      u16x4 o = {f2bf(a0), f2bf(a1), f2bf(a2), f2bf(a3)};
      __builtin_nontemporal_store(o, (u16x4*)((u16*)outv + (size_t)wid * HID + g * 16 + (cb << 2)));
    } else {
      f32x4 o = {a0, a1, a2, a3};
      __builtin_nontemporal_store(o, (f32x4*)((float*)outv + (size_t)wid * HID + g * 16 + (cb << 2)));
    }
  }
}

// ---------------- host ----------------

extern "C" void kernel_launch(void* const* d_in, const int* in_sizes, int n_in,
                              void* d_out, int out_size, void* d_ws, size_t ws_size,
                              hipStream_t stream) {
  const float* x = (const float*)d_in[0];
  const int* ei = (const int*)d_in[1];  // [2][E] int32
  const float* W1 = (const float*)d_in[2];
  const float* b1 = (const float*)d_in[3];
  const float* W2 = (const float*)d_in[4];
  const float* b2 = (const float*)d_in[5];
  float* out = (float*)d_out;

  const int N = in_sizes[0] / IN_CH;  // 100000
  const int E = in_sizes[1] / 2;      // 3200000
  const int* e_src = ei;
  const int* e_dst = ei + E;

  size_t off = 0;
  auto carve = [&](size_t bytes) -> char* {
    char* p = (char*)d_ws + off;
    off += (bytes + 255) & ~(size_t)255;
    return p;
  };
  int* bcnt = (int*)carve((size_t)NBUK * 4);
  u32* bedge = (u32*)carve((size_t)NBUK * BCAP * 4);  // 16 MB
  int* rptr = (int*)carve((size_t)N * 4);
  int* rcnt = (int*)carve((size_t)N * 4);
  float* dinv = (float*)carve((size_t)N * 4);
  u16* w1t = (u16*)carve(64 * 256 * 2);
  u16* w2t = (u16*)carve(64 * 64 * 2);
  u16* h1 = (u16*)carve((size_t)N * HID * 2);  // grouped hg[4][N][16]; reused for h2
  u16* g1 = (u16*)carve((size_t)N * HID * 2);  // standard [N][64] (gemm2 A)

  const int n_tiles = (E + TILE - 1) / TILE;  // 391
  const int nb_g1 = (N + 63) / 64;            // 64 rows per block (4 waves x 16)
  const int n_chunk = (N + 7) / 8;            // 8 nodes per chunk (2 halves x 4 waves)

  hipMemsetAsync(bcnt, 0, (size_t)NBUK * 4, stream);
  k_wprep<<<(64 * 256 + 64 * 64 + 255) / 256, 256, 0, stream>>>(W1, W2, w1t, w2t);
  k_part<<<n_tiles, 1024, 0, stream>>>(e_src, e_dst, bcnt, bedge, E);
  k_sort<<<NBUK, 1024, 0, stream>>>(bcnt, bedge, rptr, rcnt, dinv, N);
  k_gemm1<<<nb_g1, 256, 0, stream>>>(x, w1t, dinv, h1, N);
  k_agg<true, true><<<n_chunk * 8, 256, 0, stream>>>(h1, rptr, rcnt, bedge, b1, g1, N);
  k_gemm2<<<N / 16, 256, 0, stream>>>(g1, w2t, dinv, h1, N);
  k_agg<false, false><<<n_chunk * 8, 256, 0, stream>>>(h1, rptr, rcnt, bedge, b2, out, N);
}